// Round 2
// baseline (2274.558 us; speedup 1.0000x reference)
//
#include <hip/hip_runtime.h>
#include <hip/hip_bf16.h>

#define TOKENS 4096
#define HIDDEN 1024
#define FFN    2816
#define NEXP   8

// ---------------------------------------------------------------------------
// ws layout (bytes):
//   [0..31]        counts[8]        (zeroed each call)
//   [32..63]       offs[8]
//   [256..]        tok_list[8][4096] int   (131072 B)
//   [131328..]     w_list[8][4096] float   (131072 B)
//   [262400..]     hbuf[8192][2816] float  (92,274,688 B)
// total ~88.3 MiB
// ---------------------------------------------------------------------------

// -------------------- gate + top-2 (one wave per token) --------------------
__global__ __launch_bounds__(256) void gate_kernel(
    const float* __restrict__ x, const float* __restrict__ gw,
    int* __restrict__ counts, int* __restrict__ tok_list,
    float* __restrict__ w_list)
{
    __shared__ float g[NEXP * HIDDEN];   // 32 KB
    int tid = threadIdx.x;
    const float4* gw4 = (const float4*)gw;
    float4* g4 = (float4*)g;
    #pragma unroll
    for (int i = 0; i < (NEXP * HIDDEN / 4) / 256; ++i)   // 8 iters
        g4[tid + i * 256] = gw4[tid + i * 256];
    __syncthreads();

    int wave = tid >> 6, lane = tid & 63;
    int t = blockIdx.x * 4 + wave;
    const float* xr = x + (size_t)t * HIDDEN;

    float acc[NEXP] = {};
    #pragma unroll
    for (int q = 0; q < 4; ++q) {
        int k = (q * 64 + lane) * 4;              // coalesced, LDS conflict-free
        float4 xv = *(const float4*)(xr + k);
        #pragma unroll
        for (int e = 0; e < NEXP; ++e) {
            const float* ge = g + e * HIDDEN + k;
            acc[e] += xv.x * ge[0] + xv.y * ge[1] + xv.z * ge[2] + xv.w * ge[3];
        }
    }
    #pragma unroll
    for (int e = 0; e < NEXP; ++e)
        #pragma unroll
        for (int off = 32; off > 0; off >>= 1)
            acc[e] += __shfl_xor(acc[e], off);

    if (lane == 0) {
        // top-2 (strict > keeps lowest index on ties, matching lax.top_k)
        int b0 = 0; float l0 = acc[0];
        #pragma unroll
        for (int e = 1; e < NEXP; ++e) if (acc[e] > l0) { l0 = acc[e]; b0 = e; }
        int b1 = -1; float l1 = -1e30f;
        #pragma unroll
        for (int e = 0; e < NEXP; ++e)
            if (e != b0 && acc[e] > l1) { l1 = acc[e]; b1 = e; }
        // normalized top-2 softmax weights: denominator cancels exactly
        float w0 = 1.f / (1.f + __expf(l1 - l0));
        float w1 = 1.f - w0;
        int p0 = atomicAdd(&counts[b0], 1);
        tok_list[b0 * TOKENS + p0] = t;  w_list[b0 * TOKENS + p0] = w0;
        int p1 = atomicAdd(&counts[b1], 1);
        tok_list[b1 * TOKENS + p1] = t;  w_list[b1 * TOKENS + p1] = w1;
    }
}

// -------------------- tiny exclusive scan over 8 counts --------------------
__global__ void scan_kernel(const int* __restrict__ counts, int* __restrict__ offs)
{
    if (threadIdx.x == 0) {
        int s = 0;
        for (int e = 0; e < NEXP; ++e) { offs[e] = s; s += counts[e]; }
    }
}

// -------------------- phase A: h = silu(X@W1^T) * (X@W3^T) -----------------
// grouped GEMM, tile 128(M tokens) x 64(N ffn), BK=16, dual-B fused
#define A_BM 128
#define A_BN 64
#define A_BK 16

__global__ __launch_bounds__(256) void ffn_gate_up(
    const float* __restrict__ x, const float* __restrict__ w1,
    const float* __restrict__ w3, const int* __restrict__ counts,
    const int* __restrict__ offs, const int* __restrict__ tok_list,
    float* __restrict__ hbuf)
{
    int e   = blockIdx.z;
    int cnt = counts[e];
    int m0  = blockIdx.y * A_BM;
    if (m0 >= cnt) return;
    int n0  = blockIdx.x * A_BN;

    __shared__ float Xs [A_BK][A_BM + 4];
    __shared__ float W1s[A_BK][A_BN + 4];
    __shared__ float W3s[A_BK][A_BN + 4];
    __shared__ int   toks[A_BM];

    int tid = threadIdx.x;
    if (tid < A_BM)
        toks[tid] = tok_list[e * TOKENS + min(m0 + tid, cnt - 1)];
    __syncthreads();

    int tx = tid & 15, ty = tid >> 4;     // out: rows ty*8.., cols tx*4..
    int rA = tid >> 2, qA = tid & 3;      // loaders

    const float* w1e = w1 + (size_t)e * FFN * HIDDEN;
    const float* w3e = w3 + (size_t)e * FFN * HIDDEN;
    const float* xp0 = x + (size_t)toks[rA]      * HIDDEN + qA * 4;
    const float* xp1 = x + (size_t)toks[rA + 64] * HIDDEN + qA * 4;
    const float* wp1 = w1e + (size_t)(n0 + rA) * HIDDEN + qA * 4;
    const float* wp3 = w3e + (size_t)(n0 + rA) * HIDDEN + qA * 4;

    float acc1[8][4] = {}; float acc3[8][4] = {};

    for (int kt = 0; kt < HIDDEN; kt += A_BK) {
        float4 xv0 = *(const float4*)(xp0 + kt);
        float4 xv1 = *(const float4*)(xp1 + kt);
        float4 wv1 = *(const float4*)(wp1 + kt);
        float4 wv3 = *(const float4*)(wp3 + kt);
        __syncthreads();
        Xs [qA*4+0][rA]      = xv0.x; Xs [qA*4+1][rA]      = xv0.y;
        Xs [qA*4+2][rA]      = xv0.z; Xs [qA*4+3][rA]      = xv0.w;
        Xs [qA*4+0][rA+64]   = xv1.x; Xs [qA*4+1][rA+64]   = xv1.y;
        Xs [qA*4+2][rA+64]   = xv1.z; Xs [qA*4+3][rA+64]   = xv1.w;
        W1s[qA*4+0][rA]      = wv1.x; W1s[qA*4+1][rA]      = wv1.y;
        W1s[qA*4+2][rA]      = wv1.z; W1s[qA*4+3][rA]      = wv1.w;
        W3s[qA*4+0][rA]      = wv3.x; W3s[qA*4+1][rA]      = wv3.y;
        W3s[qA*4+2][rA]      = wv3.z; W3s[qA*4+3][rA]      = wv3.w;
        __syncthreads();
        #pragma unroll
        for (int kk = 0; kk < A_BK; ++kk) {
            float xa[8], b1[4], b3[4];
            *(float4*)&xa[0] = *(const float4*)&Xs[kk][ty * 8];
            *(float4*)&xa[4] = *(const float4*)&Xs[kk][ty * 8 + 4];
            *(float4*)&b1[0] = *(const float4*)&W1s[kk][tx * 4];
            *(float4*)&b3[0] = *(const float4*)&W3s[kk][tx * 4];
            #pragma unroll
            for (int i = 0; i < 8; ++i)
                #pragma unroll
                for (int j = 0; j < 4; ++j) {
                    acc1[i][j] += xa[i] * b1[j];
                    acc3[i][j] += xa[i] * b3[j];
                }
        }
    }

    int hbase = offs[e] + m0;
    #pragma unroll
    for (int i = 0; i < 8; ++i) {
        int r = ty * 8 + i;
        if (m0 + r < cnt) {
            float4 hv;
            float z;
            z = acc1[i][0]; hv.x = z / (1.f + __expf(-z)) * acc3[i][0];
            z = acc1[i][1]; hv.y = z / (1.f + __expf(-z)) * acc3[i][1];
            z = acc1[i][2]; hv.z = z / (1.f + __expf(-z)) * acc3[i][2];
            z = acc1[i][3]; hv.w = z / (1.f + __expf(-z)) * acc3[i][3];
            *(float4*)(hbuf + (size_t)(hbase + r) * FFN + n0 + tx * 4) = hv;
        }
    }
}

// -------------------- phase B: out += ew * (h @ W2^T) ----------------------
// tile 128(M) x 128(N hidden), BK=16
#define B_BM 128
#define B_BN 128
#define B_BK 16

__global__ __launch_bounds__(256) void ffn_down(
    const float* __restrict__ hbuf, const float* __restrict__ w2,
    const int* __restrict__ counts, const int* __restrict__ offs,
    const int* __restrict__ tok_list, const float* __restrict__ w_list,
    float* __restrict__ out)
{
    int e   = blockIdx.z;
    int cnt = counts[e];
    int m0  = blockIdx.y * B_BM;
    if (m0 >= cnt) return;
    int n0  = blockIdx.x * B_BN;

    __shared__ float Hs [B_BK][B_BM + 4];
    __shared__ float W2s[B_BK][B_BN + 4];

    int tid = threadIdx.x;
    int tx = tid & 15, ty = tid >> 4;
    int rA = tid >> 2, qA = tid & 3;

    int hbase = offs[e] + m0;
    int rl0 = min(rA,      cnt - 1 - m0);
    int rl1 = min(rA + 64, cnt - 1 - m0);
    const float* h0  = hbuf + (size_t)(hbase + rl0) * FFN + qA * 4;
    const float* h1  = hbuf + (size_t)(hbase + rl1) * FFN + qA * 4;
    const float* w2e = w2 + (size_t)e * HIDDEN * FFN;
    const float* wp0 = w2e + (size_t)(n0 + rA)      * FFN + qA * 4;
    const float* wp1 = w2e + (size_t)(n0 + rA + 64) * FFN + qA * 4;

    float acc[8][8] = {};

    for (int kt = 0; kt < FFN; kt += B_BK) {
        float4 hv0 = *(const float4*)(h0 + kt);
        float4 hv1 = *(const float4*)(h1 + kt);
        float4 wv0 = *(const float4*)(wp0 + kt);
        float4 wv1 = *(const float4*)(wp1 + kt);
        __syncthreads();
        Hs [qA*4+0][rA]    = hv0.x; Hs [qA*4+1][rA]    = hv0.y;
        Hs [qA*4+2][rA]    = hv0.z; Hs [qA*4+3][rA]    = hv0.w;
        Hs [qA*4+0][rA+64] = hv1.x; Hs [qA*4+1][rA+64] = hv1.y;
        Hs [qA*4+2][rA+64] = hv1.z; Hs [qA*4+3][rA+64] = hv1.w;
        W2s[qA*4+0][rA]    = wv0.x; W2s[qA*4+1][rA]    = wv0.y;
        W2s[qA*4+2][rA]    = wv0.z; W2s[qA*4+3][rA]    = wv0.w;
        W2s[qA*4+0][rA+64] = wv1.x; W2s[qA*4+1][rA+64] = wv1.y;
        W2s[qA*4+2][rA+64] = wv1.z; W2s[qA*4+3][rA+64] = wv1.w;
        __syncthreads();
        #pragma unroll
        for (int kk = 0; kk < B_BK; ++kk) {
            float xa[8], b[8];
            *(float4*)&xa[0] = *(const float4*)&Hs[kk][ty * 8];
            *(float4*)&xa[4] = *(const float4*)&Hs[kk][ty * 8 + 4];
            *(float4*)&b[0]  = *(const float4*)&W2s[kk][tx * 8];
            *(float4*)&b[4]  = *(const float4*)&W2s[kk][tx * 8 + 4];
            #pragma unroll
            for (int i = 0; i < 8; ++i)
                #pragma unroll
                for (int j = 0; j < 8; ++j)
                    acc[i][j] += xa[i] * b[j];
        }
    }

    #pragma unroll
    for (int i = 0; i < 8; ++i) {
        int r = ty * 8 + i;
        if (m0 + r < cnt) {
            int   tok = tok_list[e * TOKENS + m0 + r];
            float ew  = w_list [e * TOKENS + m0 + r];
            float* orow = out + (size_t)tok * HIDDEN + n0 + tx * 8;
            #pragma unroll
            for (int j = 0; j < 8; ++j)
                atomicAdd(orow + j, acc[i][j] * ew);
        }
    }
}

// ---------------------------------------------------------------------------
extern "C" void kernel_launch(void* const* d_in, const int* in_sizes, int n_in,
                              void* d_out, int out_size, void* d_ws, size_t ws_size,
                              hipStream_t stream)
{
    const float* x  = (const float*)d_in[0];
    const float* gw = (const float*)d_in[1];
    const float* w1 = (const float*)d_in[2];
    const float* w2 = (const float*)d_in[3];
    const float* w3 = (const float*)d_in[4];
    float* out = (float*)d_out;

    int*   counts   = (int*)d_ws;
    int*   offs     = counts + 8;
    int*   tok_list = (int*)((char*)d_ws + 256);
    float* w_list   = (float*)((char*)d_ws + 256 + NEXP * TOKENS * 4);
    float* hbuf     = (float*)((char*)d_ws + 256 + 2 * NEXP * TOKENS * 4);

    hipMemsetAsync(d_ws, 0, 64, stream);                       // counts/offs
    hipMemsetAsync(d_out, 0, (size_t)TOKENS * HIDDEN * 4, stream);

    gate_kernel<<<TOKENS / 4, 256, 0, stream>>>(x, gw, counts, tok_list, w_list);
    scan_kernel<<<1, 64, 0, stream>>>(counts, offs);
    ffn_gate_up<<<dim3(FFN / A_BN, TOKENS / A_BM, NEXP), 256, 0, stream>>>(
        x, w1, w3, counts, offs, tok_list, hbuf);
    ffn_down<<<dim3(HIDDEN / B_BN, TOKENS / B_BM, NEXP), 256, 0, stream>>>(
        hbuf, w2, counts, offs, tok_list, w_list, out);
}

// Round 3
// 997.744 us; speedup vs baseline: 2.2797x; 2.2797x over previous
//
#include <hip/hip_runtime.h>
#include <hip/hip_bf16.h>

#define TOKENS 4096
#define HIDDEN 1024
#define FFN    2816
#define NEXP   8

typedef __attribute__((ext_vector_type(8))) short bf16x8;   // 8 bf16 = 4 VGPR
typedef __attribute__((ext_vector_type(4))) float f32x4;    // MFMA acc

#define MFMA16(A,B,C) __builtin_amdgcn_mfma_f32_16x16x32_bf16((A),(B),(C),0,0,0)

__device__ __forceinline__ unsigned short f2bf(float f) {   // RNE f32->bf16
    unsigned u = __float_as_uint(f);
    return (unsigned short)((u + 0x7fffu + ((u >> 16) & 1u)) >> 16);
}
__device__ __forceinline__ float bf2f(unsigned short h) {
    return __uint_as_float(((unsigned)h) << 16);
}
// split v into hi bf16 + lo bf16 (residual), store 4 of each (8B writes)
__device__ __forceinline__ void split_store(unsigned short* hi, unsigned short* lo, float4 v) {
    ushort4 h, l;
    h.x = f2bf(v.x); l.x = f2bf(v.x - bf2f(h.x));
    h.y = f2bf(v.y); l.y = f2bf(v.y - bf2f(h.y));
    h.z = f2bf(v.z); l.z = f2bf(v.z - bf2f(h.z));
    h.w = f2bf(v.w); l.w = f2bf(v.w - bf2f(h.w));
    *(ushort4*)hi = h;
    *(ushort4*)lo = l;
}
__device__ __forceinline__ void bf_store(unsigned short* d, float4 v) {
    ushort4 h;
    h.x = f2bf(v.x); h.y = f2bf(v.y); h.z = f2bf(v.z); h.w = f2bf(v.w);
    *(ushort4*)d = h;
}

// -------------------- gate + top-2 (one wave per token) --------------------
__global__ __launch_bounds__(256) void gate_kernel(
    const float* __restrict__ x, const float* __restrict__ gw,
    int* __restrict__ counts, int* __restrict__ tok_list,
    float* __restrict__ w_list)
{
    __shared__ float g[NEXP * HIDDEN];   // 32 KB
    int tid = threadIdx.x;
    const float4* gw4 = (const float4*)gw;
    float4* g4 = (float4*)g;
    #pragma unroll
    for (int i = 0; i < (NEXP * HIDDEN / 4) / 256; ++i)
        g4[tid + i * 256] = gw4[tid + i * 256];
    __syncthreads();

    int wave = tid >> 6, lane = tid & 63;
    int t = blockIdx.x * 4 + wave;
    const float* xr = x + (size_t)t * HIDDEN;

    float acc[NEXP] = {};
    #pragma unroll
    for (int q = 0; q < 4; ++q) {
        int k = (q * 64 + lane) * 4;
        float4 xv = *(const float4*)(xr + k);
        #pragma unroll
        for (int e = 0; e < NEXP; ++e) {
            const float* ge = g + e * HIDDEN + k;
            acc[e] += xv.x * ge[0] + xv.y * ge[1] + xv.z * ge[2] + xv.w * ge[3];
        }
    }
    #pragma unroll
    for (int e = 0; e < NEXP; ++e)
        #pragma unroll
        for (int off = 32; off > 0; off >>= 1)
            acc[e] += __shfl_xor(acc[e], off);

    if (lane == 0) {
        int b0 = 0; float l0 = acc[0];
        #pragma unroll
        for (int e = 1; e < NEXP; ++e) if (acc[e] > l0) { l0 = acc[e]; b0 = e; }
        int b1 = -1; float l1 = -1e30f;
        #pragma unroll
        for (int e = 0; e < NEXP; ++e)
            if (e != b0 && acc[e] > l1) { l1 = acc[e]; b1 = e; }
        float w0 = 1.f / (1.f + __expf(l1 - l0));
        float w1 = 1.f - w0;
        int p0 = atomicAdd(&counts[b0], 1);
        tok_list[b0 * TOKENS + p0] = t;  w_list[b0 * TOKENS + p0] = w0;
        int p1 = atomicAdd(&counts[b1], 1);
        tok_list[b1 * TOKENS + p1] = t;  w_list[b1 * TOKENS + p1] = w1;
    }
}

__global__ void scan_kernel(const int* __restrict__ counts, int* __restrict__ offs)
{
    if (threadIdx.x == 0) {
        int s = 0;
        for (int e = 0; e < NEXP; ++e) { offs[e] = s; s += counts[e]; }
    }
}

// -------------------- x -> xh + xl (hi/lo bf16 split) ----------------------
__global__ __launch_bounds__(256) void xsplit_kernel(
    const float* __restrict__ x, unsigned short* __restrict__ xh,
    unsigned short* __restrict__ xl)
{
    int i = blockIdx.x * 256 + threadIdx.x;       // float4 index
    float4 v = ((const float4*)x)[i];
    ushort4 h, l;
    h.x = f2bf(v.x); l.x = f2bf(v.x - bf2f(h.x));
    h.y = f2bf(v.y); l.y = f2bf(v.y - bf2f(h.y));
    h.z = f2bf(v.z); l.z = f2bf(v.z - bf2f(h.z));
    h.w = f2bf(v.w); l.w = f2bf(v.w - bf2f(h.w));
    ((ushort4*)xh)[i] = h;
    ((ushort4*)xl)[i] = l;
}

// ---------------------------------------------------------------------------
// Phase A: h = silu(X@W1^T) * (X@W3^T), split-bf16 (3-term) MFMA.
// Tile 128(M tok) x 64(N ffn) per weight, BK=32 (one mfma K). 4 waves (2x2).
// A-frags direct from global xh/xl (prefetched); W staged in LDS hi/lo, dbuf.
// ---------------------------------------------------------------------------
#define A_BM 128
#define A_BN 64
#define A_BK 32
#define LDA  40   // LDS row stride (bf16): 80B -> max 2-way bank conflict, 16B-aligned

__global__ __launch_bounds__(256, 2) void ffn_gate_up(
    const unsigned short* __restrict__ xh, const unsigned short* __restrict__ xl,
    const float* __restrict__ w1, const float* __restrict__ w3,
    const int* __restrict__ counts, const int* __restrict__ offs,
    const int* __restrict__ tok_list, unsigned short* __restrict__ hbuf)
{
    const int e   = blockIdx.z;
    const int cnt = counts[e];
    const int m0  = blockIdx.y * A_BM;
    if (m0 >= cnt) return;
    const int n0  = blockIdx.x * A_BN;

    __shared__ alignas(16) unsigned short Wt[2][4][A_BN * LDA]; // w1h,w1l,w3h,w3l: 40 KB

    const int tid  = threadIdx.x;
    const int lane = tid & 63, wid = tid >> 6;
    const int wr   = wid >> 1, wc = wid & 1;     // wave 2x2 over 128x64
    const int lm   = lane & 15, lk = lane >> 4;

    // W staging: thread covers rows (srw, srw+32) of both w1 and w3, 4 fp32 @ skw
    const int srw = tid >> 3;
    const int skw = (tid & 7) * 4;
    const float* w1p = w1 + (size_t)e * FFN * HIDDEN + (size_t)(n0 + srw) * HIDDEN + skw;
    const float* w3p = w3 + (size_t)e * FFN * HIDDEN + (size_t)(n0 + srw) * HIDDEN + skw;

    // A-fragment global base pointers (per mf), row = token of this lane
    const unsigned short* axh[4];
    const unsigned short* axl[4];
    #pragma unroll
    for (int mf = 0; mf < 4; ++mf) {
        int r = min(m0 + wr * 64 + mf * 16 + lm, cnt - 1);
        int t = tok_list[e * TOKENS + r];
        axh[mf] = xh + (size_t)t * HIDDEN + lk * 8;
        axl[mf] = xl + (size_t)t * HIDDEN + lk * 8;
    }

    f32x4 acc1[4][2] = {};
    f32x4 acc3[4][2] = {};

    // prologue: stage W(0) + load A(0)
    {
        float4 W1a = *(const float4*)(w1p);
        float4 W1b = *(const float4*)(w1p + 32 * HIDDEN);
        float4 W3a = *(const float4*)(w3p);
        float4 W3b = *(const float4*)(w3p + 32 * HIDDEN);
        split_store(&Wt[0][0][srw * LDA + skw],        &Wt[0][1][srw * LDA + skw],        W1a);
        split_store(&Wt[0][0][(srw + 32) * LDA + skw], &Wt[0][1][(srw + 32) * LDA + skw], W1b);
        split_store(&Wt[0][2][srw * LDA + skw],        &Wt[0][3][srw * LDA + skw],        W3a);
        split_store(&Wt[0][2][(srw + 32) * LDA + skw], &Wt[0][3][(srw + 32) * LDA + skw], W3b);
    }
    bf16x8 ah[4], al[4];
    #pragma unroll
    for (int mf = 0; mf < 4; ++mf) {
        ah[mf] = *(const bf16x8*)(axh[mf]);
        al[mf] = *(const bf16x8*)(axl[mf]);
    }
    __syncthreads();

    const int bbase = (wc * 32 + lm) * LDA + lk * 8;
    const int NK = HIDDEN / A_BK;   // 32

    for (int kt = 0; kt < NK; ++kt) {
        const int cur  = kt & 1;
        const bool more = (kt + 1 < NK);
        float4 W1a, W1b, W3a, W3b;
        bf16x8 ahn[4], aln[4];
        if (more) {                      // issue next-step loads early (hide under MFMA)
            const int ko = (kt + 1) * A_BK;
            W1a = *(const float4*)(w1p + ko);
            W1b = *(const float4*)(w1p + 32 * HIDDEN + ko);
            W3a = *(const float4*)(w3p + ko);
            W3b = *(const float4*)(w3p + 32 * HIDDEN + ko);
            #pragma unroll
            for (int mf = 0; mf < 4; ++mf) {
                ahn[mf] = *(const bf16x8*)(axh[mf] + ko);
                aln[mf] = *(const bf16x8*)(axl[mf] + ko);
            }
        }
        // B-frags from LDS
        bf16x8 b1h[2], b1l[2], b3h[2], b3l[2];
        #pragma unroll
        for (int nf = 0; nf < 2; ++nf) {
            b1h[nf] = *(const bf16x8*)&Wt[cur][0][bbase + nf * 16 * LDA];
            b1l[nf] = *(const bf16x8*)&Wt[cur][1][bbase + nf * 16 * LDA];
            b3h[nf] = *(const bf16x8*)&Wt[cur][2][bbase + nf * 16 * LDA];
            b3l[nf] = *(const bf16x8*)&Wt[cur][3][bbase + nf * 16 * LDA];
        }
        #pragma unroll
        for (int mf = 0; mf < 4; ++mf)
            #pragma unroll
            for (int nf = 0; nf < 2; ++nf) {
                acc1[mf][nf] = MFMA16(ah[mf], b1h[nf], acc1[mf][nf]);
                acc1[mf][nf] = MFMA16(ah[mf], b1l[nf], acc1[mf][nf]);
                acc1[mf][nf] = MFMA16(al[mf], b1h[nf], acc1[mf][nf]);
                acc3[mf][nf] = MFMA16(ah[mf], b3h[nf], acc3[mf][nf]);
                acc3[mf][nf] = MFMA16(ah[mf], b3l[nf], acc3[mf][nf]);
                acc3[mf][nf] = MFMA16(al[mf], b3h[nf], acc3[mf][nf]);
            }
        if (more) {
            split_store(&Wt[cur ^ 1][0][srw * LDA + skw],        &Wt[cur ^ 1][1][srw * LDA + skw],        W1a);
            split_store(&Wt[cur ^ 1][0][(srw + 32) * LDA + skw], &Wt[cur ^ 1][1][(srw + 32) * LDA + skw], W1b);
            split_store(&Wt[cur ^ 1][2][srw * LDA + skw],        &Wt[cur ^ 1][3][srw * LDA + skw],        W3a);
            split_store(&Wt[cur ^ 1][2][(srw + 32) * LDA + skw], &Wt[cur ^ 1][3][(srw + 32) * LDA + skw], W3b);
            #pragma unroll
            for (int mf = 0; mf < 4; ++mf) { ah[mf] = ahn[mf]; al[mf] = aln[mf]; }
            __syncthreads();
        }
    }

    // epilogue: silu(acc1)*acc3 -> bf16 hbuf
    const int hbase = offs[e] + m0;
    #pragma unroll
    for (int mf = 0; mf < 4; ++mf) {
        const int rbase = wr * 64 + mf * 16 + lk * 4;
        #pragma unroll
        for (int i = 0; i < 4; ++i) {
            const int r = rbase + i;
            if (m0 + r < cnt) {
                unsigned short* hrow = hbuf + (size_t)(hbase + r) * FFN + n0 + wc * 32 + lm;
                #pragma unroll
                for (int nf = 0; nf < 2; ++nf) {
                    float z = acc1[mf][nf][i];
                    float s = z / (1.f + __expf(-z));
                    hrow[nf * 16] = f2bf(s * acc3[mf][nf][i]);
                }
            }
        }
    }
}

// ---------------------------------------------------------------------------
// Phase B: out += ew * (H @ W2^T), pure bf16 MFMA.
// Tile 128(M) x 128(N hidden), BK=32. H-frags direct from global bf16 hbuf.
// ---------------------------------------------------------------------------
#define B_BM 128
#define B_BN 128
#define B_BK 32
#define LDB  40

__global__ __launch_bounds__(256, 2) void ffn_down(
    const unsigned short* __restrict__ hbuf, const float* __restrict__ w2,
    const int* __restrict__ counts, const int* __restrict__ offs,
    const int* __restrict__ tok_list, const float* __restrict__ w_list,
    float* __restrict__ out)
{
    const int e   = blockIdx.z;
    const int cnt = counts[e];
    const int m0  = blockIdx.y * B_BM;
    if (m0 >= cnt) return;
    const int n0  = blockIdx.x * B_BN;

    __shared__ alignas(16) unsigned short Ws[2][B_BN * LDB];   // 20 KB

    const int tid  = threadIdx.x;
    const int lane = tid & 63, wid = tid >> 6;
    const int wr   = wid >> 1, wc = wid & 1;     // wave 2x2 over 128x128
    const int lm   = lane & 15, lk = lane >> 4;

    // W2 staging: thread covers rows n0+srw+{0,32,64,96}, 4 fp32 @ skw
    const int srw = tid >> 3;
    const int skw = (tid & 7) * 4;
    const float* w2p = w2 + (size_t)e * HIDDEN * FFN + (size_t)(n0 + srw) * FFN + skw;

    // H fragment base pointers (per mf)
    const int hb = offs[e];
    const unsigned short* ahp[4];
    #pragma unroll
    for (int mf = 0; mf < 4; ++mf) {
        int r = min(m0 + wr * 64 + mf * 16 + lm, cnt - 1);
        ahp[mf] = hbuf + (size_t)(hb + r) * FFN + lk * 8;
    }

    f32x4 acc[4][4] = {};

    {   // prologue
        float4 Wv0 = *(const float4*)(w2p);
        float4 Wv1 = *(const float4*)(w2p + 32 * (size_t)FFN);
        float4 Wv2 = *(const float4*)(w2p + 64 * (size_t)FFN);
        float4 Wv3 = *(const float4*)(w2p + 96 * (size_t)FFN);
        bf_store(&Ws[0][srw * LDB + skw],        Wv0);
        bf_store(&Ws[0][(srw + 32) * LDB + skw], Wv1);
        bf_store(&Ws[0][(srw + 64) * LDB + skw], Wv2);
        bf_store(&Ws[0][(srw + 96) * LDB + skw], Wv3);
    }
    bf16x8 ah[4];
    #pragma unroll
    for (int mf = 0; mf < 4; ++mf) ah[mf] = *(const bf16x8*)(ahp[mf]);
    __syncthreads();

    const int bbase = (wc * 64 + lm) * LDB + lk * 8;
    const int NK = FFN / B_BK;   // 88

    for (int kt = 0; kt < NK; ++kt) {
        const int cur  = kt & 1;
        const bool more = (kt + 1 < NK);
        float4 Wv0, Wv1, Wv2, Wv3;
        bf16x8 ahn[4];
        if (more) {
            const int ko = (kt + 1) * B_BK;
            Wv0 = *(const float4*)(w2p + ko);
            Wv1 = *(const float4*)(w2p + 32 * (size_t)FFN + ko);
            Wv2 = *(const float4*)(w2p + 64 * (size_t)FFN + ko);
            Wv3 = *(const float4*)(w2p + 96 * (size_t)FFN + ko);
            #pragma unroll
            for (int mf = 0; mf < 4; ++mf) ahn[mf] = *(const bf16x8*)(ahp[mf] + ko);
        }
        bf16x8 bh[4];
        #pragma unroll
        for (int nf = 0; nf < 4; ++nf)
            bh[nf] = *(const bf16x8*)&Ws[cur][bbase + nf * 16 * LDB];
        #pragma unroll
        for (int mf = 0; mf < 4; ++mf)
            #pragma unroll
            for (int nf = 0; nf < 4; ++nf)
                acc[mf][nf] = MFMA16(ah[mf], bh[nf], acc[mf][nf]);
        if (more) {
            bf_store(&Ws[cur ^ 1][srw * LDB + skw],        Wv0);
            bf_store(&Ws[cur ^ 1][(srw + 32) * LDB + skw], Wv1);
            bf_store(&Ws[cur ^ 1][(srw + 64) * LDB + skw], Wv2);
            bf_store(&Ws[cur ^ 1][(srw + 96) * LDB + skw], Wv3);
            #pragma unroll
            for (int mf = 0; mf < 4; ++mf) ah[mf] = ahn[mf];
            __syncthreads();
        }
    }

    // epilogue: weighted atomic accumulate
    #pragma unroll
    for (int mf = 0; mf < 4; ++mf) {
        const int rbase = wr * 64 + mf * 16 + lk * 4;
        #pragma unroll
        for (int i = 0; i < 4; ++i) {
            const int r = rbase + i;
            if (m0 + r < cnt) {
                const int   tok = tok_list[e * TOKENS + m0 + r];
                const float ew  = w_list [e * TOKENS + m0 + r];
                float* orow = out + (size_t)tok * HIDDEN + n0 + wc * 64 + lm;
                #pragma unroll
                for (int nf = 0; nf < 4; ++nf)
                    atomicAdd(orow + nf * 16, acc[mf][nf][i] * ew);
            }
        }
    }
}

// ---------------------------------------------------------------------------
extern "C" void kernel_launch(void* const* d_in, const int* in_sizes, int n_in,
                              void* d_out, int out_size, void* d_ws, size_t ws_size,
                              hipStream_t stream)
{
    const float* x  = (const float*)d_in[0];
    const float* gw = (const float*)d_in[1];
    const float* w1 = (const float*)d_in[2];
    const float* w2 = (const float*)d_in[3];
    const float* w3 = (const float*)d_in[4];
    float* out = (float*)d_out;

    // ws layout (63.2 MB total; R2 verified >= 88 MB available)
    int*   counts   = (int*)d_ws;
    int*   offs     = counts + 8;
    int*   tok_list = (int*)((char*)d_ws + 256);
    float* w_list   = (float*)((char*)d_ws + 256 + NEXP * TOKENS * 4);
    unsigned short* hbuf = (unsigned short*)((char*)d_ws + 262400);                  // 46.1 MB bf16
    unsigned short* xhB  = (unsigned short*)((char*)d_ws + 46399744);                // 8.4 MB
    unsigned short* xlB  = (unsigned short*)((char*)d_ws + 46399744 + 8388608);      // 8.4 MB

    hipMemsetAsync(d_ws, 0, 64, stream);
    hipMemsetAsync(d_out, 0, (size_t)TOKENS * HIDDEN * 4, stream);

    xsplit_kernel<<<TOKENS * HIDDEN / 1024, 256, 0, stream>>>(x, xhB, xlB);
    gate_kernel<<<TOKENS / 4, 256, 0, stream>>>(x, gw, counts, tok_list, w_list);
    scan_kernel<<<1, 64, 0, stream>>>(counts, offs);
    ffn_gate_up<<<dim3(FFN / A_BN, TOKENS / A_BM, NEXP), 256, 0, stream>>>(
        xhB, xlB, w1, w3, counts, offs, tok_list, hbuf);
    ffn_down<<<dim3(HIDDEN / B_BN, TOKENS / B_BM, NEXP), 256, 0, stream>>>(
        hbuf, w2, counts, offs, tok_list, w_list, out);
}